// Round 8
// baseline (163.854 us; speedup 1.0000x reference)
//
#include <hip/hip_runtime.h>
#include <hip/hip_bf16.h>

typedef unsigned short u16;
typedef _Float16 f16;
typedef __attribute__((ext_vector_type(8))) _Float16 f16x8;
typedef __attribute__((ext_vector_type(2))) __fp16 h16x2;   // cvt_pkrtz return type
typedef __attribute__((ext_vector_type(8))) short short8;
typedef __attribute__((ext_vector_type(4))) float f32x4;

#define B_ 4
#define T_ 2048
#define D_ 512
#define H_ 8
#define M_ (B_*T_)          // 8192 rows
#define INV2PI 0.15915494309189535f

// ---- static device workspace ----
__device__ f16 g_qb[M_*D_];                // normalized q /2pi   8 MB
__device__ f16 g_kb[M_*D_];                // normalized k        8 MB
__device__ f16 g_kTp[(size_t)B_*H_*64*T_]; // k^T, slot-permuted  8 MB
__device__ f16 g_fA[(size_t)M_*D_];        // force half kh=0     8 MB
__device__ f16 g_fB[(size_t)M_*D_];        // force half kh=1     8 MB

__device__ inline float sin2pi(float x) {
#if __has_builtin(__builtin_amdgcn_sinf)
  return __builtin_amdgcn_sinf(x);   // v_sin_f32: sin(2*pi*x)
#else
  return __sinf(x * 6.283185307179586f);
#endif
}

// 8x fp32 -> fp16x8 via packed RTZ converts (1 instr per pair)
__device__ inline f16x8 cvt8h(f32x4 a, f32x4 b) {
  union { h16x2 h[4]; f16x8 v; } u;
  u.h[0] = __builtin_amdgcn_cvt_pkrtz(a[0], a[1]);
  u.h[1] = __builtin_amdgcn_cvt_pkrtz(a[2], a[3]);
  u.h[2] = __builtin_amdgcn_cvt_pkrtz(b[0], b[1]);
  u.h[3] = __builtin_amdgcn_cvt_pkrtz(b[2], b[3]);
  return u.v;
}

// slot permutation for the PV A-operand register layout:
// position p (0..31) in permuted storage holds original k = perm5(p)
__device__ inline int perm5(int p) {
  int lg = p >> 3, e = p & 7;
  return (e < 4) ? lg*4 + e : 16 + lg*4 + (e & 3);
}

// ---- GEMM C[m,n] = sum_k A[m,k]*Bt[n,k]  (K=512), fp16 MFMA ----
// XCD-panel swizzle: all n-blocks of one m-panel land on the same XCD, so the
// fp32 A-panel is HBM-fetched once and L2-hit for the remaining n-blocks.
// MODE 0: z @ Wqk^T, epilogue = per-64-chunk l2-normalize -> g_qb (x 1/2pi) / g_kb
// MODE 1: (g_fA+g_fB) @ Wout^T + omega + b_out -> Cout fp32
template<int MODE>
__global__ __launch_bounds__(256, 2)
void gemm_bt(float* __restrict__ Cout, const float* __restrict__ add1,
             const float* __restrict__ add2, const float* __restrict__ Afp,
             const float* __restrict__ Bfp) {
  constexpr int K = 512;
  constexpr int N = (MODE == 0) ? 1024 : 512;
  constexpr int NB = N/128;                 // n-blocks per m-panel
  __shared__ f16 As[128*72];
  __shared__ f16 Bs[128*72];
  const int bidx = blockIdx.x;
  const int xcd = bidx & 7, idx = bidx >> 3;
  const int mp = xcd + 8*(idx/NB);          // m-panel: fixed per XCD set
  const int np = idx % NB;
  const int m0 = mp*128, n0 = np*128;
  const int t = threadIdx.x;
  const int w = t>>6, l = t&63;
  const int wr = (w>>1)*64, wc = (w&1)*64;
  const int lg = l>>4, li = l&15;
  const int srow = t>>3, scol = (t&7)*8;

  f32x4 acc[4][4] = {};

  for (int k0 = 0; k0 < K; k0 += 64) {
#pragma unroll
    for (int p = 0; p < 4; ++p) {
      int r = srow + p*32;
      {
        f32x4 b0 = *(const f32x4*)&Bfp[(size_t)(n0+r)*K + k0 + scol];
        f32x4 b1 = *(const f32x4*)&Bfp[(size_t)(n0+r)*K + k0 + scol + 4];
        *(f16x8*)&Bs[r*72 + scol] = cvt8h(b0, b1);
      }
      if (MODE == 0) {
        f32x4 a0 = *(const f32x4*)&Afp[(size_t)(m0+r)*K + k0 + scol];
        f32x4 a1 = *(const f32x4*)&Afp[(size_t)(m0+r)*K + k0 + scol + 4];
        *(f16x8*)&As[r*72 + scol] = cvt8h(a0, a1);
      } else {
        f16x8 a = *(const f16x8*)&g_fA[(size_t)(m0+r)*K + k0 + scol];
        f16x8 c = *(const f16x8*)&g_fB[(size_t)(m0+r)*K + k0 + scol];
        *(f16x8*)&As[r*72 + scol] = a + c;
      }
    }
    __syncthreads();
#pragma unroll
    for (int ks = 0; ks < 2; ++ks) {
      f16x8 af[4], bf[4];
#pragma unroll
      for (int i = 0; i < 4; ++i)
        af[i] = *(const f16x8*)&As[(wr + i*16 + li)*72 + ks*32 + lg*8];
#pragma unroll
      for (int j = 0; j < 4; ++j)
        bf[j] = *(const f16x8*)&Bs[(wc + j*16 + li)*72 + ks*32 + lg*8];
#pragma unroll
      for (int i = 0; i < 4; ++i)
#pragma unroll
        for (int j = 0; j < 4; ++j)
          acc[i][j] = __builtin_amdgcn_mfma_f32_16x16x32_f16(af[i], bf[j], acc[i][j], 0, 0, 0);
    }
    __syncthreads();
  }

  if (MODE == 0) {
    // fused per-head l2 normalize: each wave's 64-col tile is exactly one chunk
    const bool isq = (n0 < 512);
    f16* dst = isq ? g_qb : g_kb;
    const float qs = isq ? INV2PI : 1.0f;
    const int nb = (isq ? n0 : n0 - 512) + wc;
#pragma unroll
    for (int i = 0; i < 4; ++i) {
#pragma unroll
      for (int r = 0; r < 4; ++r) {
        float s = 0.f;
#pragma unroll
        for (int j = 0; j < 4; ++j) s += acc[i][j][r]*acc[i][j][r];
#pragma unroll
        for (int off = 1; off < 16; off <<= 1) s += __shfl_xor(s, off);
        float sc = qs / fmaxf(sqrtf(s), 1e-12f);
        int row = m0 + wr + i*16 + lg*4 + r;
#pragma unroll
        for (int j = 0; j < 4; ++j)
          dst[(size_t)row*D_ + nb + j*16 + li] = (f16)(acc[i][j][r]*sc);
      }
    }
  } else {
#pragma unroll
    for (int i = 0; i < 4; ++i) {
#pragma unroll
      for (int j = 0; j < 4; ++j) {
        int col = n0 + wc + j*16 + li;
        float badd = add1[col] + add2[col];
#pragma unroll
        for (int r = 0; r < 4; ++r) {
          int row = m0 + wr + i*16 + lg*4 + r;
          Cout[(size_t)row*N + col] = acc[i][j][r] + badd;
        }
      }
    }
  }
}

// ---- transpose k to [bh][d][t'] with PV slot permutation baked in ----
__global__ void transpose_k_kernel() {
  __shared__ u16 tile[64*72];
  const int t0 = blockIdx.x*64, bh = blockIdx.y;
  const int b = bh>>3, h = bh&7;
  const int t = threadIdx.x;
  const u16* kb = (const u16*)g_kb;
  u16* kT = (u16*)g_kTp;
  {
    int r = t>>2, cs = (t&3)*16;
    const u16* src = kb + (size_t)(b*T_ + t0 + r)*D_ + h*64 + cs;
    *(short8*)&tile[r*72 + cs]     = *(const short8*)(src);
    *(short8*)&tile[r*72 + cs + 8] = *(const short8*)(src + 8);
  }
  __syncthreads();
  {
    int d = t>>2, ts = (t&3)*16;
    short8 o0, o1;
#pragma unroll
    for (int j = 0; j < 8; ++j) {
      int p0 = ts + j, p1 = ts + 8 + j;
      int s0 = (p0 & ~31) | perm5(p0 & 31);
      int s1 = (p1 & ~31) | perm5(p1 & 31);
      o0[j] = (short)tile[s0*72 + d];
      o1[j] = (short)tile[s1*72 + d];
    }
    u16* dst = kT + ((size_t)bh*64 + d)*T_ + t0 + ts;
    *(short8*)(dst)     = o0;
    *(short8*)(dst + 8) = o1;
  }
}

// ---- fused  force = sin(Q K^T) K  per (b,h) ----
// R5 launch structure (grid 512, kt-split x2, 2 blocks/CU = 2 waves/SIMD for
// TLP) + fp16 body with cvt_pkrtz (1-instr pack vs ~5-op bf16 RNE) + T15
// 2-deep QK/sinPV interleave + T5 setprio around MFMA clusters.
__global__ __launch_bounds__(256, 2)
void kuramoto_attn_kernel() {
  __shared__ u16 Ks[2][128*72];
  __shared__ u16 KTs[2][64*136];
  const int wg  = blockIdx.x;
  const int wgp = (wg & 7)*64 + (wg >> 3);   // XCD swizzle: 4 bh per XCD
  const int bh = wgp >> 4, qt = (wgp & 15) >> 1, kh = wgp & 1;
  const int b = bh >> 3, h = bh & 7;
  const int t = threadIdx.x;
  const int w = t>>6, l = t&63;
  const int lg = l>>4, li = l&15;

  // loop-invariant Q fragments (32 VGPR): wave w owns q rows w*64..w*64+63
  f16x8 bq[2][4];
#pragma unroll
  for (int ks = 0; ks < 2; ++ks)
#pragma unroll
    for (int j = 0; j < 4; ++j)
      bq[ks][j] = *(const f16x8*)&g_qb[(size_t)(b*T_ + qt*256 + w*64 + j*16 + li)*D_
                                       + h*64 + ks*32 + lg*8];

  const int sr = t>>3, sc = (t&7)*8;        // Ks staging coords (128x64)
  const int sd = t>>4, sk = (t&15)*8;       // KTs staging coords (64x128)
  const u16* kbase = (const u16*)g_kb  + (size_t)b*T_*D_ + h*64;
  const u16* tbase = (const u16*)g_kTp + (size_t)bh*64*T_;
  const int kt0 = kh*8;

  f32x4 acc_o[4][4] = {};

  // prologue: stage kt0 into buffer 0
#pragma unroll
  for (int p = 0; p < 4; ++p) {
    *(short8*)&Ks[0][(sr + p*32)*72 + sc] =
      *(const short8*)&kbase[(size_t)(kt0*128 + sr + p*32)*D_ + sc];
    *(short8*)&KTs[0][(sd + p*16)*136 + sk] =
      *(const short8*)&tbase[(size_t)(sd + p*16)*T_ + kt0*128 + sk];
  }
  __syncthreads();

#define QK_STEP(KKP, S) do {                                                   \
  _Pragma("unroll") for (int ks = 0; ks < 2; ++ks) {                           \
    f16x8 af0 = *(const f16x8*)&Ks[buf][((2*(KKP)  )*16 + li)*72 + ks*32 + lg*8]; \
    f16x8 af1 = *(const f16x8*)&Ks[buf][((2*(KKP)+1)*16 + li)*72 + ks*32 + lg*8]; \
    __builtin_amdgcn_s_setprio(1);                                             \
    _Pragma("unroll") for (int j = 0; j < 4; ++j) {                            \
      S[0][j] = __builtin_amdgcn_mfma_f32_16x16x32_f16(af0, bq[ks][j], S[0][j], 0,0,0); \
      S[1][j] = __builtin_amdgcn_mfma_f32_16x16x32_f16(af1, bq[ks][j], S[1][j], 0,0,0); \
    }                                                                          \
    __builtin_amdgcn_s_setprio(0); } } while(0)

#define SINPV_STEP(KKP, S) do {                                                \
  f16x8 apv[4];                                                                \
  _Pragma("unroll") for (int j = 0; j < 4; ++j) {                              \
    union { h16x2 h[4]; f16x8 v; } cv;                                         \
    cv.h[0] = __builtin_amdgcn_cvt_pkrtz(sin2pi(S[0][j][0]), sin2pi(S[0][j][1])); \
    cv.h[1] = __builtin_amdgcn_cvt_pkrtz(sin2pi(S[0][j][2]), sin2pi(S[0][j][3])); \
    cv.h[2] = __builtin_amdgcn_cvt_pkrtz(sin2pi(S[1][j][0]), sin2pi(S[1][j][1])); \
    cv.h[3] = __builtin_amdgcn_cvt_pkrtz(sin2pi(S[1][j][2]), sin2pi(S[1][j][3])); \
    apv[j] = cv.v; }                                                           \
  _Pragma("unroll") for (int di = 0; di < 4; ++di) {                           \
    f16x8 bv = *(const f16x8*)&KTs[buf][(di*16 + li)*136 + (KKP)*32 + lg*8];   \
    __builtin_amdgcn_s_setprio(1);                                             \
    _Pragma("unroll") for (int j = 0; j < 4; ++j)                              \
      acc_o[j][di] = __builtin_amdgcn_mfma_f32_16x16x32_f16(apv[j], bv, acc_o[j][di], 0,0,0); \
    __builtin_amdgcn_s_setprio(0);                                             \
  } } while(0)

#pragma unroll 2
  for (int ii = 0; ii < 8; ++ii) {
    const int buf = ii & 1;
    // issue next-tile global loads early (hidden under compute)
    short8 rk[4], rt[4];
    if (ii < 7) {
      const int ktn = kt0 + ii + 1;
#pragma unroll
      for (int p = 0; p < 4; ++p) {
        rk[p] = *(const short8*)&kbase[(size_t)(ktn*128 + sr + p*32)*D_ + sc];
        rt[p] = *(const short8*)&tbase[(size_t)(sd + p*16)*T_ + ktn*128 + sk];
      }
    }

    // 2-deep pipelined compute: QK[kkp+1] in flight while sin/PV[kkp] runs
    f32x4 sA[2][4] = {};
    f32x4 sB[2][4] = {};
    QK_STEP(0, sA);
    QK_STEP(1, sB);  SINPV_STEP(0, sA);
#pragma unroll
    for (int z = 0; z < 2; ++z)
#pragma unroll
      for (int j = 0; j < 4; ++j) sA[z][j] = (f32x4)(0.f);
    QK_STEP(2, sA);  SINPV_STEP(1, sB);
#pragma unroll
    for (int z = 0; z < 2; ++z)
#pragma unroll
      for (int j = 0; j < 4; ++j) sB[z][j] = (f32x4)(0.f);
    QK_STEP(3, sB);  SINPV_STEP(2, sA);
                     SINPV_STEP(3, sB);

    // late ds_write of the prefetched tile into the other buffer
    if (ii < 7) {
#pragma unroll
      for (int p = 0; p < 4; ++p) {
        *(short8*)&Ks[buf^1][(sr + p*32)*72 + sc] = rk[p];
        *(short8*)&KTs[buf^1][(sd + p*16)*136 + sk] = rt[p];
      }
    }
    __syncthreads();
  }
#undef QK_STEP
#undef SINPV_STEP

  // write force half fp16 (row-major [b*T+t][h*64+d])
  f16* F = kh ? g_fB : g_fA;
#pragma unroll
  for (int j = 0; j < 4; ++j)
#pragma unroll
    for (int di = 0; di < 4; ++di)
#pragma unroll
      for (int r = 0; r < 4; ++r) {
        int row = b*T_ + qt*256 + w*64 + j*16 + lg*4 + r;
        int col = h*64 + di*16 + li;
        F[(size_t)row*D_ + col] = (f16)acc_o[j][di][r];
      }
}

extern "C" void kernel_launch(void* const* d_in, const int* in_sizes, int n_in,
                              void* d_out, int out_size, void* d_ws, size_t ws_size,
                              hipStream_t stream) {
  // inputs: t(unused), z, omega, W_qk, W_out, b_out  (all fp32)
  const float* z     = (const float*)d_in[1];
  const float* omega = (const float*)d_in[2];
  const float* Wqk   = (const float*)d_in[3];
  const float* Wout  = (const float*)d_in[4];
  const float* bout  = (const float*)d_in[5];
  float* out = (float*)d_out;

  gemm_bt<0><<<512, 256, 0, stream>>>(nullptr, nullptr, nullptr, z, Wqk);
  transpose_k_kernel<<<dim3(T_/64, B_*H_), 256, 0, stream>>>();
  kuramoto_attn_kernel<<<512, 256, 0, stream>>>();
  gemm_bt<1><<<256, 256, 0, stream>>>(out, omega, bout, nullptr, Wout);
}

// Round 9
// 153.083 us; speedup vs baseline: 1.0704x; 1.0704x over previous
//
#include <hip/hip_runtime.h>
#include <hip/hip_bf16.h>

typedef unsigned short u16;
typedef _Float16 f16;
typedef __attribute__((ext_vector_type(8))) _Float16 f16x8;
typedef __attribute__((ext_vector_type(2))) __fp16 h16x2;   // cvt_pkrtz return type
typedef __attribute__((ext_vector_type(8))) short short8;
typedef __attribute__((ext_vector_type(4))) float f32x4;

#define B_ 4
#define T_ 2048
#define D_ 512
#define H_ 8
#define M_ (B_*T_)          // 8192 rows
#define INV2PI 0.15915494309189535f

// ---- static device workspace ----
__device__ f16 g_qb[M_*D_];                // normalized q /2pi   8 MB
__device__ f16 g_kb[M_*D_];                // normalized k        8 MB
__device__ f16 g_kTp[(size_t)B_*H_*64*T_]; // k^T, slot-permuted  8 MB
__device__ f16 g_fA[(size_t)M_*D_];        // force half kh=0     8 MB
__device__ f16 g_fB[(size_t)M_*D_];        // force half kh=1     8 MB

__device__ inline float sin2pi(float x) {
#if __has_builtin(__builtin_amdgcn_sinf)
  return __builtin_amdgcn_sinf(x);   // v_sin_f32: sin(2*pi*x)
#else
  return __sinf(x * 6.283185307179586f);
#endif
}

// 16B global -> LDS direct (async DMA); dest = wave-uniform base + lane*16
__device__ inline void gload16(const void* g, void* l) {
  __builtin_amdgcn_global_load_lds(
      (const __attribute__((address_space(1))) unsigned int*)g,
      (__attribute__((address_space(3))) unsigned int*)l, 16, 0, 0);
}

// 8x fp32 -> fp16x8 via packed RTZ converts (1 instr per pair)
__device__ inline f16x8 cvt8h(f32x4 a, f32x4 b) {
  union { h16x2 h[4]; f16x8 v; } u;
  u.h[0] = __builtin_amdgcn_cvt_pkrtz(a[0], a[1]);
  u.h[1] = __builtin_amdgcn_cvt_pkrtz(a[2], a[3]);
  u.h[2] = __builtin_amdgcn_cvt_pkrtz(b[0], b[1]);
  u.h[3] = __builtin_amdgcn_cvt_pkrtz(b[2], b[3]);
  return u.v;
}

// slot permutation for the PV A-operand register layout:
// position p (0..31) in permuted storage holds original k = perm5(p)
__device__ inline int perm5(int p) {
  int lg = p >> 3, e = p & 7;
  return (e < 4) ? lg*4 + e : 16 + lg*4 + (e & 3);
}

// ---- GEMM C[m,n] = sum_k A[m,k]*Bt[n,k]  (K=512), fp16 MFMA ----
// 2D grid, x (m) fastest: consecutive blocks share the B-panel (L2-resident),
// A-panels each fetched once. (R8's 1D XCD swizzle regressed ~13us - reverted.)
// MODE 0: z @ Wqk^T, epilogue = per-64-chunk l2-normalize -> g_qb (x 1/2pi) / g_kb
// MODE 1: (g_fA+g_fB) @ Wout^T + omega + b_out -> Cout fp32
template<int MODE>
__global__ __launch_bounds__(256, 2)
void gemm_bt(float* __restrict__ Cout, const float* __restrict__ add1,
             const float* __restrict__ add2, const float* __restrict__ Afp,
             const float* __restrict__ Bfp) {
  constexpr int K = 512;
  constexpr int N = (MODE == 0) ? 1024 : 512;
  __shared__ f16 As[128*72];
  __shared__ f16 Bs[128*72];
  const int m0 = blockIdx.x*128, n0 = blockIdx.y*128;
  const int t = threadIdx.x;
  const int w = t>>6, l = t&63;
  const int wr = (w>>1)*64, wc = (w&1)*64;
  const int lg = l>>4, li = l&15;
  const int srow = t>>3, scol = (t&7)*8;

  f32x4 acc[4][4] = {};

  for (int k0 = 0; k0 < K; k0 += 64) {
#pragma unroll
    for (int p = 0; p < 4; ++p) {
      int r = srow + p*32;
      {
        f32x4 b0 = *(const f32x4*)&Bfp[(size_t)(n0+r)*K + k0 + scol];
        f32x4 b1 = *(const f32x4*)&Bfp[(size_t)(n0+r)*K + k0 + scol + 4];
        *(f16x8*)&Bs[r*72 + scol] = cvt8h(b0, b1);
      }
      if (MODE == 0) {
        f32x4 a0 = *(const f32x4*)&Afp[(size_t)(m0+r)*K + k0 + scol];
        f32x4 a1 = *(const f32x4*)&Afp[(size_t)(m0+r)*K + k0 + scol + 4];
        *(f16x8*)&As[r*72 + scol] = cvt8h(a0, a1);
      } else {
        f16x8 a = *(const f16x8*)&g_fA[(size_t)(m0+r)*K + k0 + scol];
        f16x8 c = *(const f16x8*)&g_fB[(size_t)(m0+r)*K + k0 + scol];
        *(f16x8*)&As[r*72 + scol] = a + c;
      }
    }
    __syncthreads();
#pragma unroll
    for (int ks = 0; ks < 2; ++ks) {
      f16x8 af[4], bf[4];
#pragma unroll
      for (int i = 0; i < 4; ++i)
        af[i] = *(const f16x8*)&As[(wr + i*16 + li)*72 + ks*32 + lg*8];
#pragma unroll
      for (int j = 0; j < 4; ++j)
        bf[j] = *(const f16x8*)&Bs[(wc + j*16 + li)*72 + ks*32 + lg*8];
#pragma unroll
      for (int i = 0; i < 4; ++i)
#pragma unroll
        for (int j = 0; j < 4; ++j)
          acc[i][j] = __builtin_amdgcn_mfma_f32_16x16x32_f16(af[i], bf[j], acc[i][j], 0, 0, 0);
    }
    __syncthreads();
  }

  if (MODE == 0) {
    // fused per-head l2 normalize: each wave's 64-col tile is exactly one chunk
    const bool isq = (n0 < 512);
    f16* dst = isq ? g_qb : g_kb;
    const float qs = isq ? INV2PI : 1.0f;
    const int nb = (isq ? n0 : n0 - 512) + wc;
#pragma unroll
    for (int i = 0; i < 4; ++i) {
#pragma unroll
      for (int r = 0; r < 4; ++r) {
        float s = 0.f;
#pragma unroll
        for (int j = 0; j < 4; ++j) s += acc[i][j][r]*acc[i][j][r];
#pragma unroll
        for (int off = 1; off < 16; off <<= 1) s += __shfl_xor(s, off);
        float sc = qs / fmaxf(sqrtf(s), 1e-12f);
        int row = m0 + wr + i*16 + lg*4 + r;
#pragma unroll
        for (int j = 0; j < 4; ++j)
          dst[(size_t)row*D_ + nb + j*16 + li] = (f16)(acc[i][j][r]*sc);
      }
    }
  } else {
#pragma unroll
    for (int i = 0; i < 4; ++i) {
#pragma unroll
      for (int j = 0; j < 4; ++j) {
        int col = n0 + wc + j*16 + li;
        float badd = add1[col] + add2[col];
#pragma unroll
        for (int r = 0; r < 4; ++r) {
          int row = m0 + wr + i*16 + lg*4 + r;
          Cout[(size_t)row*N + col] = acc[i][j][r] + badd;
        }
      }
    }
  }
}

// ---- transpose k to [bh][d][t'] with PV slot permutation baked in ----
__global__ void transpose_k_kernel() {
  __shared__ u16 tile[64*72];
  const int t0 = blockIdx.x*64, bh = blockIdx.y;
  const int b = bh>>3, h = bh&7;
  const int t = threadIdx.x;
  const u16* kb = (const u16*)g_kb;
  u16* kT = (u16*)g_kTp;
  {
    int r = t>>2, cs = (t&3)*16;
    const u16* src = kb + (size_t)(b*T_ + t0 + r)*D_ + h*64 + cs;
    *(short8*)&tile[r*72 + cs]     = *(const short8*)(src);
    *(short8*)&tile[r*72 + cs + 8] = *(const short8*)(src + 8);
  }
  __syncthreads();
  {
    int d = t>>2, ts = (t&3)*16;
    short8 o0, o1;
#pragma unroll
    for (int j = 0; j < 8; ++j) {
      int p0 = ts + j, p1 = ts + 8 + j;
      int s0 = (p0 & ~31) | perm5(p0 & 31);
      int s1 = (p1 & ~31) | perm5(p1 & 31);
      o0[j] = (short)tile[s0*72 + d];
      o1[j] = (short)tile[s1*72 + d];
    }
    u16* dst = kT + ((size_t)bh*64 + d)*T_ + t0 + ts;
    *(short8*)(dst)     = o0;
    *(short8*)(dst + 8) = o1;
  }
}

// ---- fused  force = sin(Q K^T) K  per (b,h) ----
// grid 512 (kt-split x2, 2 blocks/CU), 256-q tile, fp16 + cvt_pkrtz, T15
// 2-deep QK/sinPV interleave, T5 setprio. Staging via global_load_lds:
// linear LDS dest + inverse-XOR-swizzled global source (rule 21), reads use
// the same XOR -> Ks 2-way (free), KTs conflict-free. No reg-staging, no
// ds_writes; loads in flight across compute, drained at the barrier.
__global__ __launch_bounds__(256, 2)
void kuramoto_attn_kernel() {
  __shared__ f16 Ks[2][128*64];    // 16 KB each
  __shared__ f16 KTs[2][64*128];   // 16 KB each
  const int wg  = blockIdx.x;
  const int wgp = (wg & 7)*64 + (wg >> 3);   // XCD swizzle: 4 bh per XCD
  const int bh = wgp >> 4, qt = (wgp & 15) >> 1, kh = wgp & 1;
  const int b = bh >> 3, h = bh & 7;
  const int t = threadIdx.x;
  const int w = t>>6, l = t&63;
  const int lg = l>>4, li = l&15;

  // loop-invariant Q fragments (32 VGPR): wave w owns q rows w*64..w*64+63
  f16x8 bq[2][4];
#pragma unroll
  for (int ks = 0; ks < 2; ++ks)
#pragma unroll
    for (int j = 0; j < 4; ++j)
      bq[ks][j] = *(const f16x8*)&g_qb[(size_t)(b*T_ + qt*256 + w*64 + j*16 + li)*D_
                                       + h*64 + ks*32 + lg*8];

  const f16* kbase = g_kb  + (size_t)b*T_*D_ + h*64;
  const f16* tbase = g_kTp + (size_t)bh*64*T_;
  const int kt0 = kh*8;

  // async stage of one kt tile into buffer bufi:
  // Ks [128 rows][8 slots of 16B], global slot = s ^ (row&7)
  // KTs [64 rows][16 slots of 16B], global slot = s ^ (row&15)
#define STAGE(BUFI, KT) do {                                                   \
  _Pragma("unroll") for (int p = 0; p < 4; ++p) {                              \
    int idx = (w*4+p)*64 + l;                                                  \
    int rK = idx >> 3, sK = idx & 7;                                           \
    gload16(&kbase[(size_t)((KT)*128 + rK)*D_ + ((sK ^ (rK & 7))<<3)],         \
            &Ks[BUFI][(w*4+p)*512]);                                           \
    int rT = idx >> 4, sT = idx & 15;                                          \
    gload16(&tbase[(size_t)rT*T_ + (KT)*128 + ((sT ^ (rT & 15))<<3)],          \
            &KTs[BUFI][(w*4+p)*512]);                                          \
  } } while(0)

  f32x4 acc_o[4][4] = {};

  // prologue: stage kt0 into buffer 0 (barrier drains the DMA)
  STAGE(0, kt0);
  __syncthreads();

#define QK_STEP(KKP, S) do {                                                   \
  _Pragma("unroll") for (int ks = 0; ks < 2; ++ks) {                           \
    f16x8 af0 = *(const f16x8*)&Ks[buf][((2*(KKP)  )*16 + li)*64               \
                                        + (((ks*4+lg) ^ (li&7))<<3)];          \
    f16x8 af1 = *(const f16x8*)&Ks[buf][((2*(KKP)+1)*16 + li)*64               \
                                        + (((ks*4+lg) ^ (li&7))<<3)];          \
    __builtin_amdgcn_s_setprio(1);                                             \
    _Pragma("unroll") for (int j = 0; j < 4; ++j) {                            \
      S[0][j] = __builtin_amdgcn_mfma_f32_16x16x32_f16(af0, bq[ks][j], S[0][j], 0,0,0); \
      S[1][j] = __builtin_amdgcn_mfma_f32_16x16x32_f16(af1, bq[ks][j], S[1][j], 0,0,0); \
    }                                                                          \
    __builtin_amdgcn_s_setprio(0); } } while(0)

#define SINPV_STEP(KKP, S) do {                                                \
  f16x8 apv[4];                                                                \
  _Pragma("unroll") for (int j = 0; j < 4; ++j) {                              \
    union { h16x2 h[4]; f16x8 v; } cv;                                         \
    cv.h[0] = __builtin_amdgcn_cvt_pkrtz(sin2pi(S[0][j][0]), sin2pi(S[0][j][1])); \
    cv.h[1] = __builtin_amdgcn_cvt_pkrtz(sin2pi(S[0][j][2]), sin2pi(S[0][j][3])); \
    cv.h[2] = __builtin_amdgcn_cvt_pkrtz(sin2pi(S[1][j][0]), sin2pi(S[1][j][1])); \
    cv.h[3] = __builtin_amdgcn_cvt_pkrtz(sin2pi(S[1][j][2]), sin2pi(S[1][j][3])); \
    apv[j] = cv.v; }                                                           \
  _Pragma("unroll") for (int di = 0; di < 4; ++di) {                           \
    f16x8 bv = *(const f16x8*)&KTs[buf][(di*16 + li)*128                       \
                                        + ((((KKP)*4+lg) ^ li)<<3)];           \
    __builtin_amdgcn_s_setprio(1);                                             \
    _Pragma("unroll") for (int j = 0; j < 4; ++j)                              \
      acc_o[j][di] = __builtin_amdgcn_mfma_f32_16x16x32_f16(apv[j], bv, acc_o[j][di], 0,0,0); \
    __builtin_amdgcn_s_setprio(0);                                             \
  } } while(0)

#pragma unroll 2
  for (int ii = 0; ii < 8; ++ii) {
    const int buf = ii & 1;
    // issue next-tile DMA first: in flight across the whole compute phase
    if (ii < 7) STAGE(buf^1, kt0 + ii + 1);

    // 2-deep pipelined compute: QK[kkp+1] in flight while sin/PV[kkp] runs
    f32x4 sA[2][4] = {};
    f32x4 sB[2][4] = {};
    QK_STEP(0, sA);
    QK_STEP(1, sB);  SINPV_STEP(0, sA);
#pragma unroll
    for (int z = 0; z < 2; ++z)
#pragma unroll
      for (int j = 0; j < 4; ++j) sA[z][j] = (f32x4)(0.f);
    QK_STEP(2, sA);  SINPV_STEP(1, sB);
#pragma unroll
    for (int z = 0; z < 2; ++z)
#pragma unroll
      for (int j = 0; j < 4; ++j) sB[z][j] = (f32x4)(0.f);
    QK_STEP(3, sB);  SINPV_STEP(2, sA);
                     SINPV_STEP(3, sB);

    __syncthreads();   // drains DMA (vmcnt) + protects both buffers
  }
#undef QK_STEP
#undef SINPV_STEP
#undef STAGE

  // write force half fp16 (row-major [b*T+t][h*64+d])
  f16* F = kh ? g_fB : g_fA;
#pragma unroll
  for (int j = 0; j < 4; ++j)
#pragma unroll
    for (int di = 0; di < 4; ++di)
#pragma unroll
      for (int r = 0; r < 4; ++r) {
        int row = b*T_ + qt*256 + w*64 + j*16 + lg*4 + r;
        int col = h*64 + di*16 + li;
        F[(size_t)row*D_ + col] = (f16)acc_o[j][di][r];
      }
}

extern "C" void kernel_launch(void* const* d_in, const int* in_sizes, int n_in,
                              void* d_out, int out_size, void* d_ws, size_t ws_size,
                              hipStream_t stream) {
  // inputs: t(unused), z, omega, W_qk, W_out, b_out  (all fp32)
  const float* z     = (const float*)d_in[1];
  const float* omega = (const float*)d_in[2];
  const float* Wqk   = (const float*)d_in[3];
  const float* Wout  = (const float*)d_in[4];
  const float* bout  = (const float*)d_in[5];
  float* out = (float*)d_out;

  gemm_bt<0><<<dim3(M_/128, 1024/128), 256, 0, stream>>>(nullptr, nullptr, nullptr, z, Wqk);
  transpose_k_kernel<<<dim3(T_/64, B_*H_), 256, 0, stream>>>();
  kuramoto_attn_kernel<<<512, 256, 0, stream>>>();
  gemm_bt<1><<<dim3(M_/128, 512/128), 256, 0, stream>>>(out, omega, bout, nullptr, Wout);
}